// Round 4
// baseline (278.041 us; speedup 1.0000x reference)
//
#include <hip/hip_runtime.h>
#include <cstdint>

// ---------------------------------------------------------------------------
// Causal self-attention block: qkv GEMM (BK=64, swizzled LDS) -> flash
// attention (contiguous 128-query band blocks, 32x32 MFMA, K 4-buffer async
// LDS staging, V direct-from-L2 reg-prefetch) -> proj GEMM.
// bf16 MFMA, fp32 accumulate. B=4 S=2048 E=768 H=12 D=64.
// ---------------------------------------------------------------------------

typedef __bf16 bf16x8 __attribute__((ext_vector_type(8)));
typedef __bf16 bf16x4 __attribute__((ext_vector_type(4)));
typedef float  f32x4  __attribute__((ext_vector_type(4)));
typedef float  f32x16 __attribute__((ext_vector_type(16)));

#define MFMA16(a, b, c) __builtin_amdgcn_mfma_f32_16x16x32_bf16(a, b, c, 0, 0, 0)
#define MFMA32(a, b, c) __builtin_amdgcn_mfma_f32_32x32x16_bf16(a, b, c, 0, 0, 0)

static constexpr int Bb = 4, Ss = 2048, Ee = 768, Hh = 12, Dd = 64;
// softmax scale 1/8 folded with log2(e) so we can use raw v_exp_f32 (2^x)
#define QSCALE 0.18033688011112042f

__device__ __forceinline__ void gl2lds16(const void* g, void* l) {
  __builtin_amdgcn_global_load_lds(
      (const __attribute__((address_space(1))) void*)g,
      (__attribute__((address_space(3))) void*)l, 16, 0, 0);
}

__device__ __forceinline__ float fexp2(float x) {
#if __has_builtin(__builtin_amdgcn_exp2f)
  return __builtin_amdgcn_exp2f(x);
#else
  return exp2f(x);
#endif
}

// swap bits 2<->3: the shared MFMA k-slot permutation baked into K/V layouts
__device__ __forceinline__ int swap23(int x) {
  return (x & ~12) | ((x & 4) << 1) | ((x & 8) >> 1);
}

// ---------------------------------------------------------------------------
// prep kernels
// ---------------------------------------------------------------------------
__global__ void cast_f32_bf16(const float* __restrict__ x,
                              __bf16* __restrict__ y, int n) {
  int i = (blockIdx.x * blockDim.x + threadIdx.x) * 4;
  if (i < n) {
    float4 v = *(const float4*)(x + i);
    bf16x4 o = {(__bf16)v.x, (__bf16)v.y, (__bf16)v.z, (__bf16)v.w};
    *(bf16x4*)(y + i) = o;
  }
}

__global__ void transpose_cast(const float* __restrict__ W,
                               __bf16* __restrict__ Wt, int K, int N) {
  __shared__ float t[64][65];
  const int k0 = blockIdx.y * 64, n0 = blockIdx.x * 64;
#pragma unroll
  for (int i = 0; i < 16; ++i) {
    int lin = i * 256 + threadIdx.x;
    int r = lin >> 6, c = lin & 63;
    t[r][c] = W[(size_t)(k0 + r) * N + n0 + c];
  }
  __syncthreads();
#pragma unroll
  for (int i = 0; i < 16; ++i) {
    int lin = i * 256 + threadIdx.x;
    int r = lin >> 6, c = lin & 63;
    Wt[(size_t)(n0 + r) * K + k0 + c] = (__bf16)t[c][r];
  }
}

// ---------------------------------------------------------------------------
// m97-style GEMM, BK=64: C[M,N] = A[M,K] @ Bt[N,K]^T, 128x128 tile.
// LDS rows are 128B -> XOR-(row&7) 16B-chunk swizzle on BOTH the staging
// source address and the fragment read (conflict-free b128 reads).
// MODE 0: qkv epilogue -- bias; Q^T [bh][d][s] plain layout, prescaled,
//         8B stores; K d-index and V^T s-index permuted via swap23.
// MODE 1: proj epilogue (bias, fp32 out)
// ---------------------------------------------------------------------------
template <int MODE>
__global__ __launch_bounds__(256) void gemm_bt(
    const __bf16* __restrict__ A, const __bf16* __restrict__ Bt,
    const float* __restrict__ bias, __bf16* __restrict__ Qb,
    __bf16* __restrict__ Kb, __bf16* __restrict__ VTb,
    float* __restrict__ out, int K, int N) {
  __shared__ __align__(16) __bf16 As[128 * 64];
  __shared__ __align__(16) __bf16 Bs[128 * 64];
  const int tid = threadIdx.x;
  const int wave = tid >> 6, lane = tid & 63;
  const int quad = lane >> 4, c16 = lane & 15;
  const int m0 = blockIdx.y * 128, n0 = blockIdx.x * 128;
  const int wm = (wave >> 1) * 64, wn = (wave & 1) * 64;

  f32x4 acc[4][4] = {};

  for (int k0 = 0; k0 < K; k0 += 64) {
    __syncthreads();
#pragma unroll
    for (int i = 0; i < 4; ++i) {
      const int cb = (i * 4 + wave) * 64;        // chunk base (wave-uniform)
      const int c = cb + lane;                   // chunk id 0..1023
      const int row = c >> 3;                    // 0..127
      const int kk = ((c & 7) ^ (row & 7)) * 8;  // swizzled source column
      gl2lds16(&A[(size_t)(m0 + row) * K + k0 + kk], &As[cb * 8]);
      gl2lds16(&Bt[(size_t)(n0 + row) * K + k0 + kk], &Bs[cb * 8]);
    }
    __syncthreads();
#pragma unroll
    for (int h = 0; h < 2; ++h) {
      bf16x8 af[4], bf[4];
#pragma unroll
      for (int mi = 0; mi < 4; ++mi) {
        const int R = wm + mi * 16 + c16;
        af[mi] = *(const bf16x8*)&As[R * 64 + (((h * 4 + quad) ^ (R & 7)) * 8)];
      }
#pragma unroll
      for (int ni = 0; ni < 4; ++ni) {
        const int R = wn + ni * 16 + c16;
        bf[ni] = *(const bf16x8*)&Bs[R * 64 + (((h * 4 + quad) ^ (R & 7)) * 8)];
      }
#pragma unroll
      for (int mi = 0; mi < 4; ++mi)
#pragma unroll
        for (int ni = 0; ni < 4; ++ni)
          acc[mi][ni] = MFMA16(af[mi], bf[ni], acc[mi][ni]);
    }
  }

#pragma unroll
  for (int mi = 0; mi < 4; ++mi) {
#pragma unroll
    for (int ni = 0; ni < 4; ++ni) {
      const int gcol = n0 + wn + ni * 16 + c16;
      const float bv = bias[gcol];
      const int growb = m0 + wm + mi * 16 + quad * 4;
      if (MODE == 0) {
        const int which = gcol / Ee;
        const int e = gcol - which * Ee;
        const int hh = e >> 6, dd = e & 63;
        const int bb = growb >> 11, ss = growb & 2047;
        const size_t bh = (size_t)(bb * Hh + hh);
        if (which == 2) {  // V^T with permuted s: 4 consecutive ss stay packed
          const int ssp = swap23(ss);
          bf16x4 o;
#pragma unroll
          for (int r = 0; r < 4; ++r) o[r] = (__bf16)(acc[mi][ni][r] + bv);
          *(bf16x4*)&VTb[(bh * Dd + dd) * Ss + ssp] = o;
        } else if (which == 0) {  // Q^T [bh][d][s] plain, prescaled, 8B store
          bf16x4 o;
#pragma unroll
          for (int r = 0; r < 4; ++r)
            o[r] = (__bf16)((acc[mi][ni][r] + bv) * QSCALE);
          *(bf16x4*)&Qb[(bh * Dd + dd) * Ss + ss] = o;
        } else {  // K: permuted d
          const int ddp = swap23(dd);
#pragma unroll
          for (int r = 0; r < 4; ++r)
            Kb[(bh * Ss + ss + r) * Dd + ddp] = (__bf16)(acc[mi][ni][r] + bv);
        }
      } else {
#pragma unroll
        for (int r = 0; r < 4; ++r)
          out[(size_t)(growb + r) * N + gcol] = acc[mi][ni][r] + bv;
      }
    }
  }
}

// ---------------------------------------------------------------------------
// length-balanced (band, bh_local) assignment for flash blocks.
// Per XCD: 96 blocks = 6 bh x 16 bands; band i costs nkt = 2i+2 iterations.
// j-order interleaves classes L,S,M (period 3). Since 32 % 3 == 2, BOTH
// {3c,3c+1,3c+2} (fill-first) AND {c, c+32, c+64} (round-robin) CU triples
// get one block of each class -> per-CU iteration counts are balanced.
// ---------------------------------------------------------------------------
__device__ __forceinline__ void band_of(int j, int& band, int& bhl) {
  const int cls = j % 3, q = j / 3;
  if (cls == 0) {
    if (q < 30) { band = 15 - q / 6; bhl = q % 6; }
    else        { band = 10; bhl = q - 30; }
  } else if (cls == 1) {
    if (q < 30) { band = q / 6; bhl = q % 6; }
    else        { band = 5; bhl = q - 30; }
  } else {
    const int p = q >> 1, hi = !(q & 1);
    if (p < 4)       { band = hi ? 10 : 5; bhl = 2 + p; }
    else if (p < 10) { band = hi ? 9 : 6;  bhl = p - 4; }
    else             { band = hi ? 8 : 7;  bhl = p - 10; }
  }
}

// ---------------------------------------------------------------------------
// flash attention v8: block = one contiguous 128-query band. K staged in LDS
// (4 buffers, 2 tiles prefetched ahead, XOR-(row&7) swizzle, one raw
// s_barrier + counted vmcnt per iteration). V read DIRECTLY from global:
// the 8 b128 V fragments for tile kt are issued at the top of the iteration
// and consumed ~600+ cy later in PV, so L2 latency is hidden under QK^T +
// softmax (L2-resident: 6 bh per XCD = 3MB; L1 absorbs the 4-wave re-read).
// V loads are issued BEFORE the stage(kt+3) pair so the compiler's wait
// before PV is vmcnt(2) -- the K-prefetch pair stays in flight across PV.
// K/V global layouts carry the swap23 k-slot permutation; Q^T is plain
// [bh][d][s] (permutation folded into the one-time gather).
// ---------------------------------------------------------------------------
__global__ __launch_bounds__(256, 3) void flash_attn(
    const __bf16* __restrict__ Qb, const __bf16* __restrict__ Kb,
    const __bf16* __restrict__ VTb, const int* __restrict__ amask,
    __bf16* __restrict__ Yb) {
  const int bid = blockIdx.x;
  const int xcd = bid & 7, j = bid >> 3;
  int band, bhl;
  band_of(j, band, bhl);
  const int bh = xcd * 6 + bhl;  // 6 (b,h) per XCD for L2 locality
  const int b = bh / Hh, h = bh - b * Hh;
  const int tid = threadIdx.x, w = tid >> 6, lane = tid & 63;
  const int hl = lane >> 5, l31 = lane & 31;
  const int r7 = l31 & 7;

  const int qs = band * 128 + w * 32;
  const int qg = qs + l31;                // this lane's query
  const int ktmax = 2 * band + (w >> 1);  // last key-tile for this wave
  const int nkt = 2 * band + 2;           // block-uniform iteration count

  const __bf16* Qp = Qb + (size_t)bh * Dd * Ss;  // Q^T [d][s]
  const __bf16* Kp = Kb + (size_t)bh * Ss * Dd;
  const __bf16* Vp = VTb + (size_t)bh * Dd * Ss;

  __shared__ __align__(16) __bf16 Ksh[4 * 64 * 64];  // 4 x 8KB (K only)
  __shared__ uint64_t ballots[32];

  // Q fragments: one-time strided gather from plain Q^T; the swap23 k-slot
  // permutation folded into d: d = wd*16 + hl*4 + (jj&3) + 2*(jj&4)
  bf16x8 qf[4];
#pragma unroll
  for (int wd = 0; wd < 4; ++wd) {
    bf16x8 f;
#pragma unroll
    for (int jj = 0; jj < 8; ++jj)
      f[jj] = Qp[(size_t)(wd * 16 + hl * 4 + (jj & 3) + ((jj & 4) << 1)) * Ss +
                 qg];
    qf[wd] = f;
  }

  // precompute attention-mask ballots for all 32 key-tiles (8 per wave)
#pragma unroll
  for (int i = 0; i < 8; ++i) {
    const int t = w * 8 + i;
    const uint64_t ball = __ballot(amask[b * Ss + t * 64 + lane] != 0);
    if (lane == 0) ballots[t] = ball;
  }
  asm volatile("s_waitcnt lgkmcnt(0)" ::: "memory");  // publish own writes

  // async stage of K tile kt into buffer buf (2 gl2lds16 per thread)
  auto stage = [&](int kt, int buf) {
    __bf16* kb = &Ksh[buf * 4096];
    const char* ksrc = (const char*)(Kp + (size_t)kt * 64 * Dd);
#pragma unroll
    for (int i = 0; i < 2; ++i) {
      const int cb = i * 256 + w * 64;     // wave-uniform chunk base
      const int p = cb + lane;             // this lane's chunk 0..511
      const int row = p >> 3;
      const int cc = (p & 7) ^ (row & 7);  // XOR swizzle
      gl2lds16(ksrc + (size_t)row * 128 + cc * 16, &kb[cb * 8]);
    }
  };

  stage(0, 0);
  stage(1, 1);                 // nkt >= 2 always
  if (nkt > 2) stage(2, 2);

  f32x16 yacc[2] = {};  // Y^T[d = 32dt + (r&3)+8(r>>2)+4hl][q = l31]
  float m_i = -30000.f, l_i = 0.f;

  for (int kt = 0; kt < nkt; ++kt) {
    // counted wait for tile kt's 2 staging loads (keep kt+1/kt+2 in flight),
    // then barrier: publishes buf[kt%4], proves everyone left buf[(kt+3)%4]
    if (kt + 2 < nkt)
      asm volatile("s_waitcnt vmcnt(4)\n\ts_barrier" ::: "memory");
    else if (kt + 1 < nkt)
      asm volatile("s_waitcnt vmcnt(2)\n\ts_barrier" ::: "memory");
    else
      asm volatile("s_waitcnt vmcnt(0)\n\ts_barrier" ::: "memory");

    const bool comp = (kt <= ktmax);
    const int k0 = kt * 64;

    // early V fragment issue (direct from global/L2); consumed in PV ~600cy
    // later. Issued BEFORE the stage pair so PV's wait leaves it in flight.
    bf16x8 vfr[2][4];
    if (comp) {
#pragma unroll
      for (int dt = 0; dt < 2; ++dt)
#pragma unroll
        for (int W = 0; W < 4; ++W)
          vfr[dt][W] = *(const bf16x8*)&Vp[(size_t)(dt * 32 + l31) * Ss + k0 +
                                           W * 16 + hl * 8];
    }

    if (kt + 3 < nkt) stage(kt + 3, (kt + 3) & 3);

    if (!comp) continue;  // waves 0,1 idle only on the last tile
    const __bf16* kb = &Ksh[(kt & 3) * 4096];

    // S^T = K @ Q^T over two 32-key groups (C rows = keys, cols = queries)
    f32x16 sg[2];
    __builtin_amdgcn_s_setprio(1);
#pragma unroll
    for (int g = 0; g < 2; ++g) {
      f32x16 acc = {};
#pragma unroll
      for (int wd = 0; wd < 4; ++wd) {
        const bf16x8 kf = *(const bf16x8*)&kb[(g * 32 + l31) * 64 +
                                             (((2 * wd + hl) ^ r7) * 8)];
        acc = MFMA32(kf, qf[wd], acc);
      }
      sg[g] = acc;
    }
    __builtin_amdgcn_s_setprio(0);

    // causal mask: only tiles overlapping this wave's diagonal
    if (k0 + 63 > qs) {
#pragma unroll
      for (int g = 0; g < 2; ++g)
#pragma unroll
        for (int r = 0; r < 16; ++r) {
          const int key = k0 + g * 32 + (r & 3) + 8 * (r >> 2) + 4 * hl;
          sg[g][r] = (key <= qg) ? sg[g][r] : -30000.f;
        }
    }
    // attention mask: wave-uniform skip when tile fully valid
    const uint64_t mball = ballots[kt];
    if (mball != ~0ull) {
#pragma unroll
      for (int g = 0; g < 2; ++g)
#pragma unroll
        for (int r = 0; r < 16; ++r) {
          const int kr = g * 32 + (r & 3) + 8 * (r >> 2) + 4 * hl;
          sg[g][r] = ((mball >> kr) & 1) ? sg[g][r] : -30000.f;
        }
    }

    // online softmax in log2 domain; row = lane's q; tree-shaped reductions
    float tm[16];
#pragma unroll
    for (int r = 0; r < 16; ++r) tm[r] = fmaxf(sg[0][r], sg[1][r]);
#pragma unroll
    for (int off = 8; off >= 1; off >>= 1)
#pragma unroll
      for (int r = 0; r < 8; ++r)
        if (r < off) tm[r] = fmaxf(tm[r], tm[r + off]);
    const float mx = fmaxf(tm[0], __shfl_xor(tm[0], 32));

    // defer-max (T13): skip O/l rescale when max grows <= 2^11.5
    const bool grow = !__all(mx <= m_i + 11.5f);
    const float mnew = grow ? fmaxf(m_i, mx) : m_i;

    float ts[16];
#pragma unroll
    for (int r = 0; r < 16; ++r) {
      const float e0 = fexp2(sg[0][r] - mnew);
      const float e1 = fexp2(sg[1][r] - mnew);
      sg[0][r] = e0;
      sg[1][r] = e1;
      ts[r] = e0 + e1;
    }
#pragma unroll
    for (int off = 8; off >= 1; off >>= 1)
#pragma unroll
      for (int r = 0; r < 8; ++r)
        if (r < off) ts[r] += ts[r + off];
    const float rs = ts[0] + __shfl_xor(ts[0], 32);

    if (grow) {
      const float alpha = fexp2(m_i - mnew);
      l_i *= alpha;
      m_i = mnew;
#pragma unroll
      for (int dt = 0; dt < 2; ++dt)
#pragma unroll
        for (int r = 0; r < 16; ++r) yacc[dt][r] *= alpha;
    }
    l_i += rs;

    // P^T B-fragments = S^T C-register groups (shared k-slot permutation)
    bf16x8 pf[4];
#pragma unroll
    for (int W = 0; W < 4; ++W) {
      bf16x8 f;
#pragma unroll
      for (int jj = 0; jj < 8; ++jj)
        f[jj] = (__bf16)sg[W >> 1][8 * (W & 1) + jj];
      pf[W] = f;
    }

    // Y^T += V^T @ P^T  (V fragments prefetched from global at iter top)
    __builtin_amdgcn_s_setprio(1);
#pragma unroll
    for (int dt = 0; dt < 2; ++dt)
#pragma unroll
      for (int W = 0; W < 4; ++W)
        yacc[dt] = MFMA32(vfr[dt][W], pf[W], yacc[dt]);
    __builtin_amdgcn_s_setprio(0);
  }

  // normalize; write Y [B,S,E] bf16 (unpermuted -- feeds gemm2)
  const float inv = 1.f / l_i;
  __bf16* yrow = Yb + (size_t)(b * Ss + qg) * Ee + h * Dd;
#pragma unroll
  for (int dt = 0; dt < 2; ++dt)
#pragma unroll
    for (int sreg = 0; sreg < 4; ++sreg) {
      bf16x4 o;
#pragma unroll
      for (int r = 0; r < 4; ++r)
        o[r] = (__bf16)(yacc[dt][sreg * 4 + r] * inv);
      *(bf16x4*)&yrow[dt * 32 + sreg * 8 + hl * 4] = o;
    }
}

// ---------------------------------------------------------------------------
// launch
// ---------------------------------------------------------------------------
extern "C" void kernel_launch(void* const* d_in, const int* in_sizes, int n_in,
                              void* d_out, int out_size, void* d_ws,
                              size_t ws_size, hipStream_t stream) {
  const float* x      = (const float*)d_in[0];
  const float* W_attn = (const float*)d_in[1];
  const float* b_attn = (const float*)d_in[2];
  const float* W_proj = (const float*)d_in[3];
  const float* b_proj = (const float*)d_in[4];
  const int* att_mask = (const int*)d_in[5];
  float* out = (float*)d_out;

  char* ws = (char*)d_ws;
  __bf16* xb  = (__bf16*)(ws);              // 12,582,912  x as bf16 / later Y
  __bf16* Wat = (__bf16*)(ws + 12582912);   //  3,538,944  W_attn^T bf16
  __bf16* Wpt = (__bf16*)(ws + 16121856);   //  1,179,648  W_proj^T bf16
  __bf16* Qb  = (__bf16*)(ws + 17301504);   // Q^T [B,H,D,S] plain, x log2e/8
  __bf16* Kb  = (__bf16*)(ws + 29884416);   // K [B,H,S,D] perm
  __bf16* VTb = (__bf16*)(ws + 42467328);   // V^T [B,H,D,S] perm
  __bf16* Yb  = xb;

  cast_f32_bf16<<<6144, 256, 0, stream>>>(x, xb, Bb * Ss * Ee);
  transpose_cast<<<dim3(36, 12), 256, 0, stream>>>(W_attn, Wat, Ee, 3 * Ee);
  transpose_cast<<<dim3(12, 12), 256, 0, stream>>>(W_proj, Wpt, Ee, Ee);

  gemm_bt<0><<<dim3(18, 64), 256, 0, stream>>>(xb, Wat, b_attn, Qb, Kb, VTb,
                                               nullptr, Ee, 3 * Ee);
  flash_attn<<<768, 256, 0, stream>>>(Qb, Kb, VTb, att_mask, Yb);
  gemm_bt<1><<<dim3(6, 64), 256, 0, stream>>>(Yb, Wpt, b_proj, nullptr,
                                              nullptr, nullptr, out, Ee, Ee);
}

// Round 5
// 217.651 us; speedup vs baseline: 1.2775x; 1.2775x over previous
//
#include <hip/hip_runtime.h>
#include <cstdint>

// ---------------------------------------------------------------------------
// Causal self-attention block: qkv GEMM (BK=32, 3-buffer counted-vmcnt
// pipeline, XCD-swizzled grid) -> flash attention (contiguous 128-query band
// blocks, 32x32 MFMA, async 3-buffer K/V staging) -> proj GEMM.
// bf16 MFMA, fp32 accumulate. B=4 S=2048 E=768 H=12 D=64.
// ---------------------------------------------------------------------------

typedef __bf16 bf16x8 __attribute__((ext_vector_type(8)));
typedef __bf16 bf16x4 __attribute__((ext_vector_type(4)));
typedef float  f32x4  __attribute__((ext_vector_type(4)));
typedef float  f32x16 __attribute__((ext_vector_type(16)));

#define MFMA16(a, b, c) __builtin_amdgcn_mfma_f32_16x16x32_bf16(a, b, c, 0, 0, 0)
#define MFMA32(a, b, c) __builtin_amdgcn_mfma_f32_32x32x16_bf16(a, b, c, 0, 0, 0)

static constexpr int Bb = 4, Ss = 2048, Ee = 768, Hh = 12, Dd = 64;
// softmax scale 1/8 folded with log2(e) so we can use raw v_exp_f32 (2^x)
#define QSCALE 0.18033688011112042f

__device__ __forceinline__ void gl2lds16(const void* g, void* l) {
  __builtin_amdgcn_global_load_lds(
      (const __attribute__((address_space(1))) void*)g,
      (__attribute__((address_space(3))) void*)l, 16, 0, 0);
}

__device__ __forceinline__ float fexp2(float x) {
#if __has_builtin(__builtin_amdgcn_exp2f)
  return __builtin_amdgcn_exp2f(x);
#else
  return exp2f(x);
#endif
}

// swap bits 2<->3: the shared MFMA k-slot permutation baked into K/V layouts
__device__ __forceinline__ int swap23(int x) {
  return (x & ~12) | ((x & 4) << 1) | ((x & 8) >> 1);
}

// ---------------------------------------------------------------------------
// prep kernels
// ---------------------------------------------------------------------------
__global__ void cast_f32_bf16(const float* __restrict__ x,
                              __bf16* __restrict__ y, int n) {
  int i = (blockIdx.x * blockDim.x + threadIdx.x) * 4;
  if (i < n) {
    float4 v = *(const float4*)(x + i);
    bf16x4 o = {(__bf16)v.x, (__bf16)v.y, (__bf16)v.z, (__bf16)v.w};
    *(bf16x4*)(y + i) = o;
  }
}

__global__ void transpose_cast(const float* __restrict__ W,
                               __bf16* __restrict__ Wt, int K, int N) {
  __shared__ float t[64][65];
  const int k0 = blockIdx.y * 64, n0 = blockIdx.x * 64;
#pragma unroll
  for (int i = 0; i < 16; ++i) {
    int lin = i * 256 + threadIdx.x;
    int r = lin >> 6, c = lin & 63;
    t[r][c] = W[(size_t)(k0 + r) * N + n0 + c];
  }
  __syncthreads();
#pragma unroll
  for (int i = 0; i < 16; ++i) {
    int lin = i * 256 + threadIdx.x;
    int r = lin >> 6, c = lin & 63;
    Wt[(size_t)(n0 + r) * K + k0 + c] = (__bf16)t[c][r];
  }
}

// ---------------------------------------------------------------------------
// GEMM: C[M,N] = A[M,K] @ Bt[N,K]^T, 128x128 tile, BK=32, 3-buffer async
// pipeline (flash-proven schedule): stage tile ks+2 after one raw s_barrier,
// counted vmcnt(4) wait (own tile-ks loads complete, ks+1 stays in flight),
// never draining mid-loop. XOR-(row&3) 16B-chunk swizzle on staging source
// and fragment reads (64B LDS rows). XCD-aware grid swizzle: each XCD owns
// 8 contiguous M-panels so A-panel + B fit its private L2.
// MODE 0: qkv epilogue -- bias; Q^T [bh][d][s] plain layout, prescaled,
//         8B stores; K d-index and V^T s-index permuted via swap23.
// MODE 1: proj epilogue (bias, fp32 out)
// ---------------------------------------------------------------------------
template <int MODE>
__global__ __launch_bounds__(256, 3) void gemm_bt(
    const __bf16* __restrict__ A, const __bf16* __restrict__ Bt,
    const float* __restrict__ bias, __bf16* __restrict__ Qb,
    __bf16* __restrict__ Kb, __bf16* __restrict__ VTb,
    float* __restrict__ out, int K, int N) {
  __shared__ __align__(16) __bf16 As[3][128 * 32];  // 3 x 8KB
  __shared__ __align__(16) __bf16 Bs[3][128 * 32];  // 3 x 8KB
  const int tid = threadIdx.x;
  const int wave = tid >> 6, lane = tid & 63;
  const int quad = lane >> 4, c16 = lane & 15;

  // XCD-aware block swizzle: nwg divisible by 8; XCD x owns a contiguous
  // range of M-panels (A-panel reuse becomes L2-local).
  const int gx = gridDim.x;
  const int nwg = gx * gridDim.y;
  const int lb = blockIdx.y * gx + blockIdx.x;
  const int nb = (lb & 7) * (nwg >> 3) + (lb >> 3);
  const int m0 = (nb / gx) * 128, n0 = (nb % gx) * 128;

  const int wm = (wave >> 1) * 64, wn = (wave & 1) * 64;
  const int nsteps = K >> 5;

  // async stage of k-step ks into buffer buf (4 gl2lds16 per thread)
  auto stage = [&](int ks, int buf) {
#pragma unroll
    for (int i = 0; i < 2; ++i) {
      const int cb = i * 256 + wave * 64;        // wave-uniform chunk base
      const int c = cb + lane;                   // chunk id 0..511
      const int row = c >> 2;                    // 0..127
      const int kk = ((c & 3) ^ (row & 3)) * 8;  // swizzled source column
      gl2lds16(&A[(size_t)(m0 + row) * K + ks * 32 + kk], &As[buf][cb * 8]);
      gl2lds16(&Bt[(size_t)(n0 + row) * K + ks * 32 + kk], &Bs[buf][cb * 8]);
    }
  };

  stage(0, 0);
  stage(1, 1);

  f32x4 acc[4][4] = {};

  for (int ks = 0; ks < nsteps; ++ks) {
    // counted wait: own tile-ks loads (4) complete, tile-ks+1 stays in
    // flight; barrier publishes buf[ks%3] and frees buf[(ks+2)%3]
    if (ks + 1 < nsteps)
      asm volatile("s_waitcnt vmcnt(4)\n\ts_barrier" ::: "memory");
    else
      asm volatile("s_waitcnt vmcnt(0)\n\ts_barrier" ::: "memory");
    if (ks + 2 < nsteps) stage(ks + 2, (ks + 2) % 3);

    const __bf16* as = As[ks % 3];
    const __bf16* bs = Bs[ks % 3];
    bf16x8 af[4], bf[4];
#pragma unroll
    for (int mi = 0; mi < 4; ++mi) {
      const int R = wm + mi * 16 + c16;
      af[mi] = *(const bf16x8*)&as[R * 32 + ((quad ^ (R & 3)) * 8)];
    }
#pragma unroll
    for (int ni = 0; ni < 4; ++ni) {
      const int R = wn + ni * 16 + c16;
      bf[ni] = *(const bf16x8*)&bs[R * 32 + ((quad ^ (R & 3)) * 8)];
    }
    __builtin_amdgcn_s_setprio(1);
#pragma unroll
    for (int mi = 0; mi < 4; ++mi)
#pragma unroll
      for (int ni = 0; ni < 4; ++ni)
        acc[mi][ni] = MFMA16(af[mi], bf[ni], acc[mi][ni]);
    __builtin_amdgcn_s_setprio(0);
  }

#pragma unroll
  for (int mi = 0; mi < 4; ++mi) {
#pragma unroll
    for (int ni = 0; ni < 4; ++ni) {
      const int gcol = n0 + wn + ni * 16 + c16;
      const float bv = bias[gcol];
      const int growb = m0 + wm + mi * 16 + quad * 4;
      if (MODE == 0) {
        const int which = gcol / Ee;
        const int e = gcol - which * Ee;
        const int hh = e >> 6, dd = e & 63;
        const int bb = growb >> 11, ss = growb & 2047;
        const size_t bh = (size_t)(bb * Hh + hh);
        if (which == 2) {  // V^T with permuted s: 4 consecutive ss stay packed
          const int ssp = swap23(ss);
          bf16x4 o;
#pragma unroll
          for (int r = 0; r < 4; ++r) o[r] = (__bf16)(acc[mi][ni][r] + bv);
          *(bf16x4*)&VTb[(bh * Dd + dd) * Ss + ssp] = o;
        } else if (which == 0) {  // Q^T [bh][d][s] plain, prescaled, 8B store
          bf16x4 o;
#pragma unroll
          for (int r = 0; r < 4; ++r)
            o[r] = (__bf16)((acc[mi][ni][r] + bv) * QSCALE);
          *(bf16x4*)&Qb[(bh * Dd + dd) * Ss + ss] = o;
        } else {  // K: permuted d
          const int ddp = swap23(dd);
#pragma unroll
          for (int r = 0; r < 4; ++r)
            Kb[(bh * Ss + ss + r) * Dd + ddp] = (__bf16)(acc[mi][ni][r] + bv);
        }
      } else {
#pragma unroll
        for (int r = 0; r < 4; ++r)
          out[(size_t)(growb + r) * N + gcol] = acc[mi][ni][r] + bv;
      }
    }
  }
}

// ---------------------------------------------------------------------------
// length-balanced (band, bh_local) assignment for flash blocks.
// Per XCD: 96 blocks = 6 bh x 16 bands; band i costs nkt = 2i+2 iterations.
// j-order interleaves classes L,S,M (period 3). Since 32 % 3 == 2, BOTH
// {3c,3c+1,3c+2} (fill-first) AND {c, c+32, c+64} (round-robin) CU triples
// get one block of each class -> per-CU iteration counts are balanced.
// ---------------------------------------------------------------------------
__device__ __forceinline__ void band_of(int j, int& band, int& bhl) {
  const int cls = j % 3, q = j / 3;
  if (cls == 0) {
    if (q < 30) { band = 15 - q / 6; bhl = q % 6; }
    else        { band = 10; bhl = q - 30; }
  } else if (cls == 1) {
    if (q < 30) { band = q / 6; bhl = q % 6; }
    else        { band = 5; bhl = q - 30; }
  } else {
    const int p = q >> 1, hi = !(q & 1);
    if (p < 4)       { band = hi ? 10 : 5; bhl = 2 + p; }
    else if (p < 10) { band = hi ? 9 : 6;  bhl = p - 4; }
    else             { band = hi ? 8 : 7;  bhl = p - 10; }
  }
}

// ---------------------------------------------------------------------------
// flash attention v7 (round-3 proven, 59.5us): block = one contiguous
// 128-query band (wave w gets queries [128*band + 32w, +32)); async 3-buffer
// K/V staging via global_load_lds with XOR-(row&7) 16B-chunk swizzle; one
// raw s_barrier + counted vmcnt per iteration; prefetch a full iteration
// ahead. K/V layouts carry the swap23 k-slot permutation; Q^T is plain
// [bh][d][s] (permutation folded into the one-time gather).
// ---------------------------------------------------------------------------
__global__ __launch_bounds__(256, 3) void flash_attn(
    const __bf16* __restrict__ Qb, const __bf16* __restrict__ Kb,
    const __bf16* __restrict__ VTb, const int* __restrict__ amask,
    __bf16* __restrict__ Yb) {
  const int bid = blockIdx.x;
  const int xcd = bid & 7, j = bid >> 3;
  int band, bhl;
  band_of(j, band, bhl);
  const int bh = xcd * 6 + bhl;  // 6 (b,h) per XCD for L2 locality
  const int b = bh / Hh, h = bh - b * Hh;
  const int tid = threadIdx.x, w = tid >> 6, lane = tid & 63;
  const int hl = lane >> 5, l31 = lane & 31;
  const int r7 = l31 & 7;

  const int qs = band * 128 + w * 32;
  const int qg = qs + l31;                // this lane's query
  const int ktmax = 2 * band + (w >> 1);  // last key-tile for this wave
  const int nkt = 2 * band + 2;           // block-uniform iteration count

  const __bf16* Qp = Qb + (size_t)bh * Dd * Ss;  // Q^T [d][s]
  const __bf16* Kp = Kb + (size_t)bh * Ss * Dd;
  const __bf16* Vp = VTb + (size_t)bh * Dd * Ss;

  __shared__ __align__(16) __bf16 Ksh[3 * 64 * 64];  // 3 x 8KB
  __shared__ __align__(16) __bf16 Vsh[3 * 64 * 64];  // 3 x 8KB
  __shared__ uint64_t ballots[32];

  // Q fragments: one-time strided gather from plain Q^T; the swap23 k-slot
  // permutation folded into d: d = wd*16 + hl*4 + (jj&3) + 2*(jj&4)
  bf16x8 qf[4];
#pragma unroll
  for (int wd = 0; wd < 4; ++wd) {
    bf16x8 f;
#pragma unroll
    for (int jj = 0; jj < 8; ++jj)
      f[jj] = Qp[(size_t)(wd * 16 + hl * 4 + (jj & 3) + ((jj & 4) << 1)) * Ss +
                 qg];
    qf[wd] = f;
  }

  // precompute attention-mask ballots for all 32 key-tiles (8 per wave)
#pragma unroll
  for (int i = 0; i < 8; ++i) {
    const int t = w * 8 + i;
    const uint64_t ball = __ballot(amask[b * Ss + t * 64 + lane] != 0);
    if (lane == 0) ballots[t] = ball;
  }
  asm volatile("s_waitcnt lgkmcnt(0)" ::: "memory");  // publish own writes

  // async stage of tile kt into buffer buf (4 gl2lds16 per thread)
  auto stage = [&](int kt, int buf) {
    __bf16* kb = &Ksh[buf * 4096];
    __bf16* vb = &Vsh[buf * 4096];
    const char* ksrc = (const char*)(Kp + (size_t)kt * 64 * Dd);
    const char* vsrc = (const char*)Vp + (size_t)kt * 128;
#pragma unroll
    for (int i = 0; i < 2; ++i) {
      const int cb = i * 256 + w * 64;        // wave-uniform chunk base
      const int p = cb + lane;                // this lane's chunk 0..511
      const int row = p >> 3;
      const int cc = (p & 7) ^ (row & 7);     // XOR swizzle
      gl2lds16(ksrc + (size_t)row * 128 + cc * 16, &kb[cb * 8]);
      gl2lds16(vsrc + (size_t)row * 4096 + cc * 16, &vb[cb * 8]);
    }
  };

  stage(0, 0);
  stage(1, 1);  // nkt >= 2 always

  f32x16 yacc[2] = {};  // Y^T[d = 32dt + (r&3)+8(r>>2)+4hl][q = l31]
  float m_i = -30000.f, l_i = 0.f;

  for (int kt = 0; kt < nkt; ++kt) {
    // wait for tile kt's staging (keep kt+1's 4 loads in flight), then
    // barrier: publishes buf[kt] and proves everyone left buf[(kt+2)%3]
    if (kt + 1 < nkt)
      asm volatile("s_waitcnt vmcnt(4)\n\ts_barrier" ::: "memory");
    else
      asm volatile("s_waitcnt vmcnt(0)\n\ts_barrier" ::: "memory");
    if (kt + 2 < nkt) stage(kt + 2, (kt + 2) % 3);

    if (kt > ktmax) continue;  // waves 0,1 idle only on the last tile
    const int k0 = kt * 64;
    const __bf16* kb = &Ksh[(kt % 3) * 4096];
    const __bf16* vb = &Vsh[(kt % 3) * 4096];

    // S^T = K @ Q^T over two 32-key groups (C rows = keys, cols = queries)
    f32x16 sg[2];
    __builtin_amdgcn_s_setprio(1);
#pragma unroll
    for (int g = 0; g < 2; ++g) {
      f32x16 acc = {};
#pragma unroll
      for (int wd = 0; wd < 4; ++wd) {
        const bf16x8 kf = *(const bf16x8*)&kb[(g * 32 + l31) * 64 +
                                             (((2 * wd + hl) ^ r7) * 8)];
        acc = MFMA32(kf, qf[wd], acc);
      }
      sg[g] = acc;
    }
    __builtin_amdgcn_s_setprio(0);

    // causal mask: only tiles overlapping this wave's diagonal
    if (k0 + 63 > qs) {
#pragma unroll
      for (int g = 0; g < 2; ++g)
#pragma unroll
        for (int r = 0; r < 16; ++r) {
          const int key = k0 + g * 32 + (r & 3) + 8 * (r >> 2) + 4 * hl;
          sg[g][r] = (key <= qg) ? sg[g][r] : -30000.f;
        }
    }
    // attention mask: wave-uniform skip when tile fully valid
    const uint64_t mball = ballots[kt];
    if (mball != ~0ull) {
#pragma unroll
      for (int g = 0; g < 2; ++g)
#pragma unroll
        for (int r = 0; r < 16; ++r) {
          const int kr = g * 32 + (r & 3) + 8 * (r >> 2) + 4 * hl;
          sg[g][r] = ((mball >> kr) & 1) ? sg[g][r] : -30000.f;
        }
    }

    // online softmax in log2 domain; row = lane's q; tree-shaped reductions
    float tm[16];
#pragma unroll
    for (int r = 0; r < 16; ++r) tm[r] = fmaxf(sg[0][r], sg[1][r]);
#pragma unroll
    for (int off = 8; off >= 1; off >>= 1)
#pragma unroll
      for (int r = 0; r < 8; ++r)
        if (r < off) tm[r] = fmaxf(tm[r], tm[r + off]);
    const float mx = fmaxf(tm[0], __shfl_xor(tm[0], 32));

    // defer-max (T13): skip O/l rescale when max grows <= 2^11.5
    const bool grow = !__all(mx <= m_i + 11.5f);
    const float mnew = grow ? fmaxf(m_i, mx) : m_i;

    float ts[16];
#pragma unroll
    for (int r = 0; r < 16; ++r) {
      const float e0 = fexp2(sg[0][r] - mnew);
      const float e1 = fexp2(sg[1][r] - mnew);
      sg[0][r] = e0;
      sg[1][r] = e1;
      ts[r] = e0 + e1;
    }
#pragma unroll
    for (int off = 8; off >= 1; off >>= 1)
#pragma unroll
      for (int r = 0; r < 8; ++r)
        if (r < off) ts[r] += ts[r + off];
    const float rs = ts[0] + __shfl_xor(ts[0], 32);

    if (grow) {
      const float alpha = fexp2(m_i - mnew);
      l_i *= alpha;
      m_i = mnew;
#pragma unroll
      for (int dt = 0; dt < 2; ++dt)
#pragma unroll
        for (int r = 0; r < 16; ++r) yacc[dt][r] *= alpha;
    }
    l_i += rs;

    // P^T B-fragments = S^T C-register groups (shared k-slot permutation)
    bf16x8 pf[4];
#pragma unroll
    for (int W = 0; W < 4; ++W) {
      bf16x8 f;
#pragma unroll
      for (int jj = 0; jj < 8; ++jj)
        f[jj] = (__bf16)sg[W >> 1][8 * (W & 1) + jj];
      pf[W] = f;
    }

    // Y^T += V^T @ P^T
    __builtin_amdgcn_s_setprio(1);
#pragma unroll
    for (int dt = 0; dt < 2; ++dt)
#pragma unroll
      for (int W = 0; W < 4; ++W) {
        const bf16x8 vf = *(const bf16x8*)&vb[(dt * 32 + l31) * 64 +
                                             (((2 * W + hl) ^ r7) * 8)];
        yacc[dt] = MFMA32(vf, pf[W], yacc[dt]);
      }
    __builtin_amdgcn_s_setprio(0);
  }

  // normalize; write Y [B,S,E] bf16 (unpermuted -- feeds gemm2)
  const float inv = 1.f / l_i;
  __bf16* yrow = Yb + (size_t)(b * Ss + qg) * Ee + h * Dd;
#pragma unroll
  for (int dt = 0; dt < 2; ++dt)
#pragma unroll
    for (int sreg = 0; sreg < 4; ++sreg) {
      bf16x4 o;
#pragma unroll
      for (int r = 0; r < 4; ++r)
        o[r] = (__bf16)(yacc[dt][sreg * 4 + r] * inv);
      *(bf16x4*)&yrow[dt * 32 + sreg * 8 + hl * 4] = o;
    }
}

// ---------------------------------------------------------------------------
// launch
// ---------------------------------------------------------------------------
extern "C" void kernel_launch(void* const* d_in, const int* in_sizes, int n_in,
                              void* d_out, int out_size, void* d_ws,
                              size_t ws_size, hipStream_t stream) {
  const float* x      = (const float*)d_in[0];
  const float* W_attn = (const float*)d_in[1];
  const float* b_attn = (const float*)d_in[2];
  const float* W_proj = (const float*)d_in[3];
  const float* b_proj = (const float*)d_in[4];
  const int* att_mask = (const int*)d_in[5];
  float* out = (float*)d_out;

  char* ws = (char*)d_ws;
  __bf16* xb  = (__bf16*)(ws);              // 12,582,912  x as bf16 / later Y
  __bf16* Wat = (__bf16*)(ws + 12582912);   //  3,538,944  W_attn^T bf16
  __bf16* Wpt = (__bf16*)(ws + 16121856);   //  1,179,648  W_proj^T bf16
  __bf16* Qb  = (__bf16*)(ws + 17301504);   // Q^T [B,H,D,S] plain, x log2e/8
  __bf16* Kb  = (__bf16*)(ws + 29884416);   // K [B,H,S,D] perm
  __bf16* VTb = (__bf16*)(ws + 42467328);   // V^T [B,H,D,S] perm
  __bf16* Yb  = xb;

  cast_f32_bf16<<<6144, 256, 0, stream>>>(x, xb, Bb * Ss * Ee);
  transpose_cast<<<dim3(36, 12), 256, 0, stream>>>(W_attn, Wat, Ee, 3 * Ee);
  transpose_cast<<<dim3(12, 12), 256, 0, stream>>>(W_proj, Wpt, Ee, Ee);

  gemm_bt<0><<<dim3(18, 64), 256, 0, stream>>>(xb, Wat, b_attn, Qb, Kb, VTb,
                                               nullptr, Ee, 3 * Ee);
  flash_attn<<<768, 256, 0, stream>>>(Qb, Kb, VTb, att_mask, Yb);
  gemm_bt<1><<<dim3(6, 64), 256, 0, stream>>>(Yb, Wpt, b_proj, nullptr,
                                              nullptr, nullptr, out, Ee, Ee);
}

// Round 6
// 203.436 us; speedup vs baseline: 1.3667x; 1.0699x over previous
//
#include <hip/hip_runtime.h>
#include <cstdint>

// ---------------------------------------------------------------------------
// Causal self-attention block: fused prep -> qkv GEMM (128x128, BK=64,
// drain-style, 5 blocks/CU) -> flash attention (contiguous 128-query band
// blocks, 32x32 MFMA, async 3-buffer staging) -> proj GEMM (64x128 tile,
// 3 blocks/CU fully resident). bf16 MFMA, fp32 accumulate.
// B=4 S=2048 E=768 H=12 D=64.
// ---------------------------------------------------------------------------

typedef __bf16 bf16x8 __attribute__((ext_vector_type(8)));
typedef __bf16 bf16x4 __attribute__((ext_vector_type(4)));
typedef float  f32x4  __attribute__((ext_vector_type(4)));
typedef float  f32x16 __attribute__((ext_vector_type(16)));

#define MFMA16(a, b, c) __builtin_amdgcn_mfma_f32_16x16x32_bf16(a, b, c, 0, 0, 0)
#define MFMA32(a, b, c) __builtin_amdgcn_mfma_f32_32x32x16_bf16(a, b, c, 0, 0, 0)

static constexpr int Bb = 4, Ss = 2048, Ee = 768, Hh = 12, Dd = 64;
// softmax scale 1/8 folded with log2(e) so we can use raw v_exp_f32 (2^x)
#define QSCALE 0.18033688011112042f

__device__ __forceinline__ void gl2lds16(const void* g, void* l) {
  __builtin_amdgcn_global_load_lds(
      (const __attribute__((address_space(1))) void*)g,
      (__attribute__((address_space(3))) void*)l, 16, 0, 0);
}

__device__ __forceinline__ float fexp2(float x) {
#if __has_builtin(__builtin_amdgcn_exp2f)
  return __builtin_amdgcn_exp2f(x);
#else
  return exp2f(x);
#endif
}

// swap bits 2<->3: the shared MFMA k-slot permutation baked into K/V layouts
__device__ __forceinline__ int swap23(int x) {
  return (x & ~12) | ((x & 4) << 1) | ((x & 8) >> 1);
}

// ---------------------------------------------------------------------------
// fused prep: blocks [0,6144) cast x f32->bf16; [6144,6576) transpose-cast
// W_attn (768x2304); [6576,6720) transpose-cast W_proj (768x768).
// One launch instead of three (kills two inter-kernel gaps).
// ---------------------------------------------------------------------------
__global__ __launch_bounds__(256) void prep_all(
    const float* __restrict__ x, __bf16* __restrict__ xb,
    const float* __restrict__ Wa, __bf16* __restrict__ Wat,
    const float* __restrict__ Wp, __bf16* __restrict__ Wpt) {
  __shared__ float t[64][65];
  const int bid = blockIdx.x, tid = threadIdx.x;
  if (bid < 6144) {  // 6144*256*4 == 4*2048*768 exactly
    const int i = (bid * 256 + tid) * 4;
    float4 v = *(const float4*)(x + i);
    bf16x4 o = {(__bf16)v.x, (__bf16)v.y, (__bf16)v.z, (__bf16)v.w};
    *(bf16x4*)(xb + i) = o;
    return;
  }
  const float* W;
  __bf16* Wt;
  int K, N, bx, by;
  if (bid < 6576) {
    W = Wa; Wt = Wat; K = 768; N = 2304;
    bx = (bid - 6144) % 36; by = (bid - 6144) / 36;
  } else {
    W = Wp; Wt = Wpt; K = 768; N = 768;
    bx = (bid - 6576) % 12; by = (bid - 6576) / 12;
  }
  const int k0 = by * 64, n0 = bx * 64;
#pragma unroll
  for (int i = 0; i < 16; ++i) {
    int lin = i * 256 + tid;
    int r = lin >> 6, c = lin & 63;
    t[r][c] = W[(size_t)(k0 + r) * N + n0 + c];
  }
  __syncthreads();
#pragma unroll
  for (int i = 0; i < 16; ++i) {
    int lin = i * 256 + tid;
    int r = lin >> 6, c = lin & 63;
    Wt[(size_t)(n0 + r) * K + k0 + c] = (__bf16)t[c][r];
  }
}

// ---------------------------------------------------------------------------
// GEMM: C[M,N] = A[M,K] @ Bt[N,K]^T, TMx128 tile, BK=64, drain-style
// (r3-proven: two __syncthreads per k-step; 5 resident blocks/CU at TM=128
// cover the drain via TLP). LDS rows are 128B -> XOR-(row&7) 16B-chunk
// swizzle on BOTH the staging source address and the fragment read.
// TM=128: 32KB LDS (qkv). TM=64: 24KB LDS, grid 2x denser (proj occupancy:
// 384 blocks @1.5/CU -> 768 @3/CU fully resident).
// MODE 0: qkv epilogue -- bias; Q^T [bh][d][s] plain layout, prescaled,
//         8B stores; K d-index and V^T s-index permuted via swap23.
// MODE 1: proj epilogue (bias, fp32 out)
// ---------------------------------------------------------------------------
template <int MODE, int TM>
__global__ __launch_bounds__(256) void gemm_bt(
    const __bf16* __restrict__ A, const __bf16* __restrict__ Bt,
    const float* __restrict__ bias, __bf16* __restrict__ Qb,
    __bf16* __restrict__ Kb, __bf16* __restrict__ VTb,
    float* __restrict__ out, int K, int N) {
  __shared__ __align__(16) __bf16 As[TM * 64];
  __shared__ __align__(16) __bf16 Bs[128 * 64];
  const int tid = threadIdx.x;
  const int wave = tid >> 6, lane = tid & 63;
  const int quad = lane >> 4, c16 = lane & 15;
  const int m0 = blockIdx.y * TM, n0 = blockIdx.x * 128;
  const int wm = (wave >> 1) * (TM / 2), wn = (wave & 1) * 64;
  constexpr int MI = TM / 32;  // 16-row fragment repeats per wave (M dim)

  f32x4 acc[MI][4] = {};

  for (int k0 = 0; k0 < K; k0 += 64) {
    __syncthreads();
    if constexpr (TM == 128) {
#pragma unroll
      for (int i = 0; i < 4; ++i) {
        const int cb = (i * 4 + wave) * 64;        // chunk base (wave-uniform)
        const int c = cb + lane;                   // chunk id 0..1023
        const int row = c >> 3;                    // 0..127
        const int kk = ((c & 7) ^ (row & 7)) * 8;  // swizzled source column
        gl2lds16(&A[(size_t)(m0 + row) * K + k0 + kk], &As[cb * 8]);
        gl2lds16(&Bt[(size_t)(n0 + row) * K + k0 + kk], &Bs[cb * 8]);
      }
    } else {  // TM == 64: A = 512 chunks (wave-chunks 0..7), B = 1024 (8..23)
#pragma unroll
      for (int i = 0; i < 6; ++i) {
        const int wc = i * 4 + wave;  // wave-chunk id, uniform within wave
        if (wc < 8) {
          const int c = wc * 64 + lane;  // A chunk 0..511
          const int row = c >> 3;        // 0..63
          const int kk = ((c & 7) ^ (row & 7)) * 8;
          gl2lds16(&A[(size_t)(m0 + row) * K + k0 + kk], &As[wc * 512]);
        } else {
          const int c = (wc - 8) * 64 + lane;  // B chunk 0..1023
          const int row = c >> 3;              // 0..127
          const int kk = ((c & 7) ^ (row & 7)) * 8;
          gl2lds16(&Bt[(size_t)(n0 + row) * K + k0 + kk],
                   &Bs[(wc - 8) * 512]);
        }
      }
    }
    __syncthreads();
#pragma unroll
    for (int h = 0; h < 2; ++h) {
      bf16x8 af[MI], bf[4];
#pragma unroll
      for (int mi = 0; mi < MI; ++mi) {
        const int R = wm + mi * 16 + c16;
        af[mi] = *(const bf16x8*)&As[R * 64 + (((h * 4 + quad) ^ (R & 7)) * 8)];
      }
#pragma unroll
      for (int ni = 0; ni < 4; ++ni) {
        const int R = wn + ni * 16 + c16;
        bf[ni] = *(const bf16x8*)&Bs[R * 64 + (((h * 4 + quad) ^ (R & 7)) * 8)];
      }
#pragma unroll
      for (int mi = 0; mi < MI; ++mi)
#pragma unroll
        for (int ni = 0; ni < 4; ++ni)
          acc[mi][ni] = MFMA16(af[mi], bf[ni], acc[mi][ni]);
    }
  }

#pragma unroll
  for (int mi = 0; mi < MI; ++mi) {
#pragma unroll
    for (int ni = 0; ni < 4; ++ni) {
      const int gcol = n0 + wn + ni * 16 + c16;
      const float bv = bias[gcol];
      const int growb = m0 + wm + mi * 16 + quad * 4;
      if (MODE == 0) {
        const int which = gcol / Ee;
        const int e = gcol - which * Ee;
        const int hh = e >> 6, dd = e & 63;
        const int bb = growb >> 11, ss = growb & 2047;
        const size_t bh = (size_t)(bb * Hh + hh);
        if (which == 2) {  // V^T with permuted s: 4 consecutive ss stay packed
          const int ssp = swap23(ss);
          bf16x4 o;
#pragma unroll
          for (int r = 0; r < 4; ++r) o[r] = (__bf16)(acc[mi][ni][r] + bv);
          *(bf16x4*)&VTb[(bh * Dd + dd) * Ss + ssp] = o;
        } else if (which == 0) {  // Q^T [bh][d][s] plain, prescaled, 8B store
          bf16x4 o;
#pragma unroll
          for (int r = 0; r < 4; ++r)
            o[r] = (__bf16)((acc[mi][ni][r] + bv) * QSCALE);
          *(bf16x4*)&Qb[(bh * Dd + dd) * Ss + ss] = o;
        } else {  // K: permuted d
          const int ddp = swap23(dd);
#pragma unroll
          for (int r = 0; r < 4; ++r)
            Kb[(bh * Ss + ss + r) * Dd + ddp] = (__bf16)(acc[mi][ni][r] + bv);
        }
      } else {
#pragma unroll
        for (int r = 0; r < 4; ++r)
          out[(size_t)(growb + r) * N + gcol] = acc[mi][ni][r] + bv;
      }
    }
  }
}

// ---------------------------------------------------------------------------
// length-balanced (band, bh_local) assignment for flash blocks.
// Per XCD: 96 blocks = 6 bh x 16 bands; band i costs nkt = 2i+2 iterations.
// j-order interleaves classes L,S,M (period 3). Since 32 % 3 == 2, BOTH
// {3c,3c+1,3c+2} (fill-first) AND {c, c+32, c+64} (round-robin) CU triples
// get one block of each class -> per-CU iteration counts are balanced.
// ---------------------------------------------------------------------------
__device__ __forceinline__ void band_of(int j, int& band, int& bhl) {
  const int cls = j % 3, q = j / 3;
  if (cls == 0) {
    if (q < 30) { band = 15 - q / 6; bhl = q % 6; }
    else        { band = 10; bhl = q - 30; }
  } else if (cls == 1) {
    if (q < 30) { band = q / 6; bhl = q % 6; }
    else        { band = 5; bhl = q - 30; }
  } else {
    const int p = q >> 1, hi = !(q & 1);
    if (p < 4)       { band = hi ? 10 : 5; bhl = 2 + p; }
    else if (p < 10) { band = hi ? 9 : 6;  bhl = p - 4; }
    else             { band = hi ? 8 : 7;  bhl = p - 10; }
  }
}

// ---------------------------------------------------------------------------
// flash attention v7 (round-3 proven, 59.5us): block = one contiguous
// 128-query band (wave w gets queries [128*band + 32w, +32)); async 3-buffer
// K/V staging via global_load_lds with XOR-(row&7) 16B-chunk swizzle; one
// raw s_barrier + counted vmcnt per iteration; prefetch a full iteration
// ahead. K/V layouts carry the swap23 k-slot permutation; Q^T is plain
// [bh][d][s] (permutation folded into the one-time gather).
// ---------------------------------------------------------------------------
__global__ __launch_bounds__(256, 3) void flash_attn(
    const __bf16* __restrict__ Qb, const __bf16* __restrict__ Kb,
    const __bf16* __restrict__ VTb, const int* __restrict__ amask,
    __bf16* __restrict__ Yb) {
  const int bid = blockIdx.x;
  const int xcd = bid & 7, j = bid >> 3;
  int band, bhl;
  band_of(j, band, bhl);
  const int bh = xcd * 6 + bhl;  // 6 (b,h) per XCD for L2 locality
  const int b = bh / Hh, h = bh - b * Hh;
  const int tid = threadIdx.x, w = tid >> 6, lane = tid & 63;
  const int hl = lane >> 5, l31 = lane & 31;
  const int r7 = l31 & 7;

  const int qs = band * 128 + w * 32;
  const int qg = qs + l31;                // this lane's query
  const int ktmax = 2 * band + (w >> 1);  // last key-tile for this wave
  const int nkt = 2 * band + 2;           // block-uniform iteration count

  const __bf16* Qp = Qb + (size_t)bh * Dd * Ss;  // Q^T [d][s]
  const __bf16* Kp = Kb + (size_t)bh * Ss * Dd;
  const __bf16* Vp = VTb + (size_t)bh * Dd * Ss;

  __shared__ __align__(16) __bf16 Ksh[3 * 64 * 64];  // 3 x 8KB
  __shared__ __align__(16) __bf16 Vsh[3 * 64 * 64];  // 3 x 8KB
  __shared__ uint64_t ballots[32];

  // Q fragments: one-time strided gather from plain Q^T; the swap23 k-slot
  // permutation folded into d: d = wd*16 + hl*4 + (jj&3) + 2*(jj&4)
  bf16x8 qf[4];
#pragma unroll
  for (int wd = 0; wd < 4; ++wd) {
    bf16x8 f;
#pragma unroll
    for (int jj = 0; jj < 8; ++jj)
      f[jj] = Qp[(size_t)(wd * 16 + hl * 4 + (jj & 3) + ((jj & 4) << 1)) * Ss +
                 qg];
    qf[wd] = f;
  }

  // precompute attention-mask ballots for all 32 key-tiles (8 per wave)
#pragma unroll
  for (int i = 0; i < 8; ++i) {
    const int t = w * 8 + i;
    const uint64_t ball = __ballot(amask[b * Ss + t * 64 + lane] != 0);
    if (lane == 0) ballots[t] = ball;
  }
  asm volatile("s_waitcnt lgkmcnt(0)" ::: "memory");  // publish own writes

  // async stage of tile kt into buffer buf (4 gl2lds16 per thread)
  auto stage = [&](int kt, int buf) {
    __bf16* kb = &Ksh[buf * 4096];
    __bf16* vb = &Vsh[buf * 4096];
    const char* ksrc = (const char*)(Kp + (size_t)kt * 64 * Dd);
    const char* vsrc = (const char*)Vp + (size_t)kt * 128;
#pragma unroll
    for (int i = 0; i < 2; ++i) {
      const int cb = i * 256 + w * 64;        // wave-uniform chunk base
      const int p = cb + lane;                // this lane's chunk 0..511
      const int row = p >> 3;
      const int cc = (p & 7) ^ (row & 7);     // XOR swizzle
      gl2lds16(ksrc + (size_t)row * 128 + cc * 16, &kb[cb * 8]);
      gl2lds16(vsrc + (size_t)row * 4096 + cc * 16, &vb[cb * 8]);
    }
  };

  stage(0, 0);
  stage(1, 1);  // nkt >= 2 always

  f32x16 yacc[2] = {};  // Y^T[d = 32dt + (r&3)+8(r>>2)+4hl][q = l31]
  float m_i = -30000.f, l_i = 0.f;

  for (int kt = 0; kt < nkt; ++kt) {
    // wait for tile kt's staging (keep kt+1's 4 loads in flight), then
    // barrier: publishes buf[kt] and proves everyone left buf[(kt+2)%3]
    if (kt + 1 < nkt)
      asm volatile("s_waitcnt vmcnt(4)\n\ts_barrier" ::: "memory");
    else
      asm volatile("s_waitcnt vmcnt(0)\n\ts_barrier" ::: "memory");
    if (kt + 2 < nkt) stage(kt + 2, (kt + 2) % 3);

    if (kt > ktmax) continue;  // waves 0,1 idle only on the last tile
    const int k0 = kt * 64;
    const __bf16* kb = &Ksh[(kt % 3) * 4096];
    const __bf16* vb = &Vsh[(kt % 3) * 4096];

    // S^T = K @ Q^T over two 32-key groups (C rows = keys, cols = queries)
    f32x16 sg[2];
    __builtin_amdgcn_s_setprio(1);
#pragma unroll
    for (int g = 0; g < 2; ++g) {
      f32x16 acc = {};
#pragma unroll
      for (int wd = 0; wd < 4; ++wd) {
        const bf16x8 kf = *(const bf16x8*)&kb[(g * 32 + l31) * 64 +
                                             (((2 * wd + hl) ^ r7) * 8)];
        acc = MFMA32(kf, qf[wd], acc);
      }
      sg[g] = acc;
    }
    __builtin_amdgcn_s_setprio(0);

    // causal mask: only tiles overlapping this wave's diagonal
    if (k0 + 63 > qs) {
#pragma unroll
      for (int g = 0; g < 2; ++g)
#pragma unroll
        for (int r = 0; r < 16; ++r) {
          const int key = k0 + g * 32 + (r & 3) + 8 * (r >> 2) + 4 * hl;
          sg[g][r] = (key <= qg) ? sg[g][r] : -30000.f;
        }
    }
    // attention mask: wave-uniform skip when tile fully valid
    const uint64_t mball = ballots[kt];
    if (mball != ~0ull) {
#pragma unroll
      for (int g = 0; g < 2; ++g)
#pragma unroll
        for (int r = 0; r < 16; ++r) {
          const int kr = g * 32 + (r & 3) + 8 * (r >> 2) + 4 * hl;
          sg[g][r] = ((mball >> kr) & 1) ? sg[g][r] : -30000.f;
        }
    }

    // online softmax in log2 domain; row = lane's q; tree-shaped reductions
    float tm[16];
#pragma unroll
    for (int r = 0; r < 16; ++r) tm[r] = fmaxf(sg[0][r], sg[1][r]);
#pragma unroll
    for (int off = 8; off >= 1; off >>= 1)
#pragma unroll
      for (int r = 0; r < 8; ++r)
        if (r < off) tm[r] = fmaxf(tm[r], tm[r + off]);
    const float mx = fmaxf(tm[0], __shfl_xor(tm[0], 32));

    // defer-max (T13): skip O/l rescale when max grows <= 2^11.5
    const bool grow = !__all(mx <= m_i + 11.5f);
    const float mnew = grow ? fmaxf(m_i, mx) : m_i;

    float ts[16];
#pragma unroll
    for (int r = 0; r < 16; ++r) {
      const float e0 = fexp2(sg[0][r] - mnew);
      const float e1 = fexp2(sg[1][r] - mnew);
      sg[0][r] = e0;
      sg[1][r] = e1;
      ts[r] = e0 + e1;
    }
#pragma unroll
    for (int off = 8; off >= 1; off >>= 1)
#pragma unroll
      for (int r = 0; r < 8; ++r)
        if (r < off) ts[r] += ts[r + off];
    const float rs = ts[0] + __shfl_xor(ts[0], 32);

    if (grow) {
      const float alpha = fexp2(m_i - mnew);
      l_i *= alpha;
      m_i = mnew;
#pragma unroll
      for (int dt = 0; dt < 2; ++dt)
#pragma unroll
        for (int r = 0; r < 16; ++r) yacc[dt][r] *= alpha;
    }
    l_i += rs;

    // P^T B-fragments = S^T C-register groups (shared k-slot permutation)
    bf16x8 pf[4];
#pragma unroll
    for (int W = 0; W < 4; ++W) {
      bf16x8 f;
#pragma unroll
      for (int jj = 0; jj < 8; ++jj)
        f[jj] = (__bf16)sg[W >> 1][8 * (W & 1) + jj];
      pf[W] = f;
    }

    // Y^T += V^T @ P^T
    __builtin_amdgcn_s_setprio(1);
#pragma unroll
    for (int dt = 0; dt < 2; ++dt)
#pragma unroll
      for (int W = 0; W < 4; ++W) {
        const bf16x8 vf = *(const bf16x8*)&vb[(dt * 32 + l31) * 64 +
                                             (((2 * W + hl) ^ r7) * 8)];
        yacc[dt] = MFMA32(vf, pf[W], yacc[dt]);
      }
    __builtin_amdgcn_s_setprio(0);
  }

  // normalize; write Y [B,S,E] bf16 (unpermuted -- feeds gemm2)
  const float inv = 1.f / l_i;
  __bf16* yrow = Yb + (size_t)(b * Ss + qg) * Ee + h * Dd;
#pragma unroll
  for (int dt = 0; dt < 2; ++dt)
#pragma unroll
    for (int sreg = 0; sreg < 4; ++sreg) {
      bf16x4 o;
#pragma unroll
      for (int r = 0; r < 4; ++r)
        o[r] = (__bf16)(yacc[dt][sreg * 4 + r] * inv);
      *(bf16x4*)&yrow[dt * 32 + sreg * 8 + hl * 4] = o;
    }
}

// ---------------------------------------------------------------------------
// launch
// ---------------------------------------------------------------------------
extern "C" void kernel_launch(void* const* d_in, const int* in_sizes, int n_in,
                              void* d_out, int out_size, void* d_ws,
                              size_t ws_size, hipStream_t stream) {
  const float* x      = (const float*)d_in[0];
  const float* W_attn = (const float*)d_in[1];
  const float* b_attn = (const float*)d_in[2];
  const float* W_proj = (const float*)d_in[3];
  const float* b_proj = (const float*)d_in[4];
  const int* att_mask = (const int*)d_in[5];
  float* out = (float*)d_out;

  char* ws = (char*)d_ws;
  __bf16* xb  = (__bf16*)(ws);              // 12,582,912  x as bf16 / later Y
  __bf16* Wat = (__bf16*)(ws + 12582912);   //  3,538,944  W_attn^T bf16
  __bf16* Wpt = (__bf16*)(ws + 16121856);   //  1,179,648  W_proj^T bf16
  __bf16* Qb  = (__bf16*)(ws + 17301504);   // Q^T [B,H,D,S] plain, x log2e/8
  __bf16* Kb  = (__bf16*)(ws + 29884416);   // K [B,H,S,D] perm
  __bf16* VTb = (__bf16*)(ws + 42467328);   // V^T [B,H,D,S] perm
  __bf16* Yb  = xb;

  prep_all<<<6720, 256, 0, stream>>>(x, xb, W_attn, Wat, W_proj, Wpt);

  gemm_bt<0, 128><<<dim3(18, 64), 256, 0, stream>>>(
      xb, Wat, b_attn, Qb, Kb, VTb, nullptr, Ee, 3 * Ee);
  flash_attn<<<768, 256, 0, stream>>>(Qb, Kb, VTb, att_mask, Yb);
  gemm_bt<1, 64><<<dim3(6, 128), 256, 0, stream>>>(
      Yb, Wpt, b_proj, nullptr, nullptr, nullptr, out, Ee, Ee);
}